// Round 5
// baseline (418.139 us; speedup 1.0000x reference)
//
#include <hip/hip_runtime.h>
#include <stdint.h>

// ---------------------------------------------------------------------------
// EfficientDet post-process, multi-dispatch (grid.sync() proved ~100us/sync on
// 8-XCD gfx950 -> kernel-boundary sync instead). 4 nodes:
//   memset(hist0 16KB) ->
//   k_score   : zero 4MB aux region + per-anchor max over 80 cls + 12b hist0
//   k_hist1   : scan(hist0)->d0; 2^20-bin leaf hist + 4096-group summary
//   k_supdec  : DETERMINISTIC REDUNDANT gather (all 16 blocks rebuild the
//               identical candidate list from keys+T, no cross-block comm) +
//               decode + key-order IoU bitmatrix + last-block-ticket
//               parallel-fixpoint NMS + rank-for-output + argmax + write
// Round-4 lesson: marginal node ~15us; k_gather's only job was a consistent
// candidate->slot map (atomicAdd order). Deterministic per-block gather
// (fixed traversal + prefix-sum placement) makes the map a pure function of
// (keys, T) -> identical in every block -> gather node deleted.
// ---------------------------------------------------------------------------

#define NK 1000
#define NS 1024   // NMS slot count (>= 1000 + exact-float-tie margin)
#define NCLS 80
#define NW 16
#define HCAP 12   // per-thread gather hit cap (~Poisson(1), P(>=12)~1e-9)
typedef unsigned long long ull;

static inline __device__ unsigned fkey(float f) {
  unsigned u = __float_as_uint(f);
  return (u & 0x80000000u) ? ~u : (u | 0x80000000u);
}
static inline __device__ float fkey_inv(unsigned k) {
  unsigned u = (k & 0x80000000u) ? (k & 0x7fffffffu) : ~k;
  return __uint_as_float(u);
}

// Redundant per-block selection scan (first 256 threads participate; blockDim
// must be >= 256). Finds largest digit with suffix-count >= k and the count
// strictly above that digit. Pure function of gh -> identical across blocks.
__device__ __forceinline__ void scan_select(const unsigned* __restrict__ gh, int nbins,
                                            unsigned k, unsigned* s_sum, unsigned* s_res,
                                            unsigned& digit, unsigned& cum_above) {
  int t = threadIdx.x;
  int chunk = nbins >> 8;
  if (chunk < 1) chunk = 1;
  int base = t * chunk;
  unsigned s = 0;
  if (t < 256)
    for (int b = 0; b < chunk; ++b) s += gh[base + b];
  if (t < 256) s_sum[t] = s;
  __syncthreads();
  if (t < 256) {
    unsigned ca = 0;
    for (int u = t + 1; u < 256; ++u) ca += s_sum[u];
    if (ca < k && ca + s >= k) {  // exactly one thread
      unsigned cum = ca;
      for (int b = chunk - 1; b >= 0; --b) {
        unsigned c = gh[base + b];
        if (cum + c >= k) { s_res[0] = (unsigned)(base + b); s_res[1] = cum; break; }
        cum += c;
      }
    }
  }
  __syncthreads();
  digit = s_res[0];
  cum_above = s_res[1];
  __syncthreads();
}

// ---- K1: zero aux region + score + key + top-12-bit histogram --------------
__global__ __launch_bounds__(256) void k_score(const float* __restrict__ cla,
                                               unsigned* __restrict__ keys,
                                               unsigned* __restrict__ hist0,
                                               uint4* __restrict__ zreg, int nz4,
                                               int A) {
  __shared__ unsigned lh[4096];
  int t = threadIdx.x;
  // Zero leaf hist (4MB) + summary + meta (consumed only by later dispatches,
  // so no intra-kernel ordering needed). Replaces a second memset node.
  {
    const uint4 z = make_uint4(0u, 0u, 0u, 0u);
    int stride = gridDim.x * 256;
    for (int i = blockIdx.x * 256 + t; i < nz4; i += stride) zreg[i] = z;
  }
  for (int i = t; i < 4096; i += 256) lh[i] = 0u;
  __syncthreads();
  const int lane = t & 63, wib = t >> 6;
  const int gwave = blockIdx.x * 4 + wib, nwaves = gridDim.x * 4;
  const int q = lane >> 2, sub = lane & 3;  // 4 lanes per 320B anchor row
  const int ntask = (A + 15) >> 4;
  for (int task = gwave; task < ntask; task += nwaves) {
    int a = task * 16 + q;
    float m = -3.402823466e38f;
    if (a < A) {
      const float4* p = (const float4*)(cla + (size_t)a * NCLS);
#pragma unroll
      for (int j = 0; j < 5; ++j) {
        float4 v = p[sub + j * 4];
        m = fmaxf(m, fmaxf(fmaxf(v.x, v.y), fmaxf(v.z, v.w)));
      }
    }
    m = fmaxf(m, __shfl_xor(m, 1, 64));
    m = fmaxf(m, __shfl_xor(m, 2, 64));
    if (sub == 0 && a < A) {
      unsigned key = fkey(m);
      keys[a] = key;
      atomicAdd(&lh[key >> 20], 1u);
    }
  }
  __syncthreads();
  for (int i = t; i < 4096; i += 256) {
    unsigned c = lh[i];
    if (c) atomicAdd(&hist0[i], c);
  }
}

// ---- K2: 2^20-bin leaf histogram + 4096-group summary ----------------------
__global__ __launch_bounds__(256) void k_hist1(const unsigned* __restrict__ keys,
                                               const unsigned* __restrict__ hist0,
                                               unsigned* __restrict__ leaf,
                                               unsigned* __restrict__ summary, int A) {
  __shared__ unsigned lh[4096];
  __shared__ unsigned s_sum[256];
  __shared__ unsigned s_res[2];
  int t = threadIdx.x;
  unsigned d0, ca;
  scan_select(hist0, 4096, NK, s_sum, s_res, d0, ca);
  for (int i = t; i < 4096; i += 256) lh[i] = 0u;
  __syncthreads();
  int tid = blockIdx.x * 256 + t, nthr = gridDim.x * 256;
  for (int a = tid; a < A; a += nthr) {
    unsigned key = keys[a];
    if ((key >> 20) == d0) {
      unsigned low = key & 0xFFFFFu;
      atomicAdd(&leaf[low], 1u);       // scattered over 1M bins -> low contention
      atomicAdd(&lh[low >> 8], 1u);    // LDS-aggregated group summary
    }
  }
  __syncthreads();
  for (int i = t; i < 4096; i += 256) {
    unsigned c = lh[i];
    if (c) atomicAdd(&summary[i], c);
  }
}

// ---- K3: deterministic gather + decode + IoU + ticket + fixpoint + output --
// Every block rebuilds the IDENTICAL candidate list: T is a pure function of
// the global hists; the gather traversal (thread t owns uint4 chunks
// t, t+1024, ...) and prefix-sum slot placement are deterministic. So the
// slot->candidate map is consistent across blocks with no communication.
__global__ __launch_bounds__(1024) void k_supdec(
    const float* __restrict__ cla, const float* __restrict__ reg,
    const float* __restrict__ anchors, const int* __restrict__ hp,
    const int* __restrict__ wp, const unsigned* __restrict__ keys,
    const unsigned* __restrict__ hist0, const unsigned* __restrict__ leaf,
    const unsigned* __restrict__ summary, ull* __restrict__ sup,
    unsigned* __restrict__ meta, float* __restrict__ out, int A) {
  __shared__ unsigned s_sum[256];
  __shared__ unsigned s_res[2];
  __shared__ ull ckl[NS];
  __shared__ float4 bx[NS];
  __shared__ float ar[NS];
  __shared__ unsigned wsum[16];
  __shared__ unsigned keptm[32], notm[32];  // NS-bit kept / decided-not masks
  __shared__ int s_chg;
  __shared__ int s_last;
  int t = threadIdx.x;
  // ---- exact 32-bit threshold (identical in all blocks)
  unsigned k_rem = NK, d0, g, b, ca;
  scan_select(hist0, 4096, k_rem, s_sum, s_res, d0, ca);
  k_rem -= ca;
  scan_select(summary, 4096, k_rem, s_sum, s_res, g, ca);
  k_rem -= ca;
  scan_select(leaf + (size_t)g * 256, 256, k_rem, s_sum, s_res, b, ca);
  const unsigned T = (d0 << 20) | (g << 8) | b;  // 1000th-largest key (exact)
  // ---- deterministic redundant gather: fixed traversal, rare hits buffered
  ckl[t] = 0ull;
  unsigned ha[HCAP];  // ~1 hit/thread expected; runtime-indexed but cold
  unsigned hc = 0;
  int nv = A >> 2;
  const uint4* k4 = (const uint4*)keys;
  for (int i = t; i < nv; i += 1024) {
    uint4 v = k4[i];
    if (v.x >= T && hc < HCAP) ha[hc++] = (unsigned)(4 * i);
    if (v.y >= T && hc < HCAP) ha[hc++] = (unsigned)(4 * i + 1);
    if (v.z >= T && hc < HCAP) ha[hc++] = (unsigned)(4 * i + 2);
    if (v.w >= T && hc < HCAP) ha[hc++] = (unsigned)(4 * i + 3);
  }
  for (int a2 = (nv << 2) + t; a2 < A; a2 += 1024) {  // tail (A%4)
    if (keys[a2] >= T && hc < HCAP) ha[hc++] = (unsigned)a2;
  }
  // block-wide exclusive prefix of hit counts (deterministic placement)
  {
    int lane = t & 63, w = t >> 6;
    unsigned v = hc;
    for (int off = 1; off < 64; off <<= 1) {
      unsigned u = __shfl_up(v, off, 64);
      if (lane >= off) v += u;
    }
    if (lane == 63) wsum[w] = v;
    __syncthreads();
    unsigned wo = 0;
    for (int j = 0; j < w; ++j) wo += wsum[j];
    unsigned base = wo + v - hc;
    for (unsigned q = 0; q < hc; ++q) {
      unsigned pos = base + q;
      if (pos < NS) {
        unsigned a = ha[q];
        ckl[pos] = ((ull)keys[a] << 32) | (ull)(~a);  // (score desc, idx asc)
      }
    }
  }
  __syncthreads();
  // ---- decode: 1 slot per thread
  ull ck = ckl[t];
  float score = 0.0f;
  bool valid = false;
  if (ck != 0ull) {
    unsigned a = ~(unsigned)(ck & 0xFFFFFFFFull);
    score = fkey_inv((unsigned)(ck >> 32));
    float W1 = (float)wp[0] - 1.0f;
    float H1 = (float)hp[0] - 1.0f;
    float4 dd = ((const float4*)reg)[a];
    float4 an = ((const float4*)anchors)[a];
    float wa = an.z - an.x, haa = an.w - an.y;
    float cxa = an.x + 0.5f * wa, cya = an.y + 0.5f * haa;
    float cx = cxa + dd.x * wa, cy = cya + dd.y * haa;
    float w = wa * expf(dd.z), h = haa * expf(dd.w);
    float x1 = fminf(fmaxf(cx - 0.5f * w, 0.0f), W1);
    float y1 = fminf(fmaxf(cy - 0.5f * h, 0.0f), H1);
    float x2 = fminf(fmaxf(cx + 0.5f * w, 0.0f), W1);
    float y2 = fminf(fmaxf(cy + 0.5f * h, 0.0f), H1);
    bx[t] = make_float4(x1, y1, x2, y2);
    ar[t] = fmaxf(x2 - x1, 0.0f) * fmaxf(y2 - y1, 0.0f);
    valid = (score > 0.5f);
  } else {
    bx[t] = make_float4(0.f, 0.f, 0.f, 0.f);
    ar[t] = 0.0f;
  }
  __syncthreads();
  // ---- IoU + key-order suppression word: 16 blocks x 1024 thr = NS*NW pairs.
  // j staggered by w -> distinct bank groups across the 16 w-lanes (2-way,
  // free) instead of 16-way conflict.
  {
    int gidx = blockIdx.x * 1024 + t;
    int i = gidx >> 4, w = gidx & 15;
    ull cki = ckl[i];
    float4 bi = bx[i];
    float ai = ar[i];
    ull bits = 0ull;
    int j0 = w * 64;
#pragma unroll 4
    for (int s = 0; s < 64; ++s) {
      int jj = (s + w) & 63;
      int j = j0 + jj;
      ull ckj = ckl[j];
      if (ckj > cki) {  // j precedes i in greedy order
        float4 bj = bx[j];
        float xx1 = fmaxf(bi.x, bj.x), yy1 = fmaxf(bi.y, bj.y);
        float xx2 = fminf(bi.z, bj.z), yy2 = fminf(bi.w, bj.w);
        float inter = fmaxf(xx2 - xx1, 0.0f) * fmaxf(yy2 - yy1, 0.0f);
        float uni = ai + ar[j] - inter;
        float iou = inter / fmaxf(uni, 1e-8f);
        if (iou > 0.5f) bits |= (1ull << jj);
      }
    }
    sup[(size_t)i * NW + w] = bits;
  }
  // ---- release our sup rows, take a ticket (agent scope: per-XCD L2s are
  // not cross-coherent; consumer reads sup via agent-scope atomic loads).
  __threadfence();
  __syncthreads();
  if (t == 0) {
    unsigned done = __hip_atomic_fetch_add(&meta[1], 1u, __ATOMIC_ACQ_REL,
                                           __HIP_MEMORY_SCOPE_AGENT);
    s_last = (done == gridDim.x - 1) ? 1 : 0;
    s_chg = 0;
  }
  __syncthreads();
  if (!s_last) return;
  // ---- last block: rank (output placement + top-NK gate). LDS broadcast
  // reads: every lane scans ckl[0..NS) in the same order -> conflict-free.
  unsigned rnk = 0;
  for (int j = 0; j < NS; ++j) rnk += (ckl[j] > ck) ? 1u : 0u;
  if (t < 32) { keptm[t] = 0u; notm[t] = 0u; }
  bool active = (ck != 0ull) && (rnk < NK);
  bool decided = (!active) || (!valid);
  ull rw[NW];  // fully unrolled static indexing only -> registers, not scratch
#pragma unroll
  for (int w = 0; w < NW; ++w)
    rw[w] = __hip_atomic_load(&sup[(size_t)t * NW + w], __ATOMIC_RELAXED,
                              __HIP_MEMORY_SCOPE_AGENT);
  __syncthreads();
  // pad slots, rank>=NK ties, and invalid-score rows are force-dropped here,
  // so they can never suppress (not in keptm) and never stall pot (in notm).
  if (decided) atomicOr(&notm[t >> 5], 1u << (t & 31));
  __syncthreads();
  // ---- monotone-fixpoint greedy NMS (order = ck desc; relation pre-masked
  // by ckj>cki in the bitmatrix, so no triangle masking needed here).
  for (int round = 0; round < NS; ++round) {
    if (!decided) {
      ull hit = 0ull, pot = 0ull;
#pragma unroll
      for (int w = 0; w < NW; ++w) {
        ull km = ((ull)keptm[2 * w + 1] << 32) | (ull)keptm[2 * w];
        ull nm = ((ull)notm[2 * w + 1] << 32) | (ull)notm[2 * w];
        hit |= rw[w] & km;
        pot |= rw[w] & ~(km | nm);
      }
      if (hit) {
        decided = true;
        atomicOr(&notm[t >> 5], 1u << (t & 31));
        s_chg = 1;  // benign race: all writers store 1
      } else if (!pot) {
        decided = true;
        atomicOr(&keptm[t >> 5], 1u << (t & 31));
        s_chg = 1;
      }
    }
    __syncthreads();
    if (s_chg == 0) break;
    __syncthreads();
    if (t == 0) s_chg = 0;
    __syncthreads();
  }
  // ---- argmax class (kept rows only) + output write at rank position
  if (active) {
    bool kp = (keptm[t >> 5] >> (t & 31)) & 1u;
    int ci = 0;
    if (kp) {
      unsigned a = ~(unsigned)(ck & 0xFFFFFFFFull);
      const float* row = cla + (size_t)a * NCLS;
      float m = -3.402823466e38f;
#pragma unroll
      for (int j = 0; j < NCLS; ++j) {
        float v = row[j];
        if (v > m) { m = v; ci = j; }
      }
    }
    out[rnk] = kp ? score : 0.0f;
    out[NK + rnk] = kp ? (float)ci : -1.0f;  // int output read as float
    float4 bo = bx[t];
    ((float4*)(out + 2 * NK))[rnk] = kp ? bo : make_float4(0.f, 0.f, 0.f, 0.f);
  }
}

extern "C" void kernel_launch(void* const* d_in, const int* in_sizes, int n_in,
                              void* d_out, int out_size, void* d_ws, size_t ws_size,
                              hipStream_t stream) {
  const float* cla = (const float*)d_in[0];
  const float* reg = (const float*)d_in[1];
  const float* anchors = (const float*)d_in[2];
  const int* hp = (const int*)d_in[3];
  const int* wp = (const int*)d_in[4];
  float* out = (float*)d_out;
  int A = in_sizes[2] / 4;  // 441936

  char* ws = (char*)d_ws;
  size_t off = 0;
  auto carve = [&](size_t bytes) -> void* {
    void* p = ws + off;
    off += bytes;
    off = (off + 255) & ~(size_t)255;
    return p;
  };
  unsigned* keys = (unsigned*)carve((size_t)A * 4);
  unsigned* hist0 = (unsigned*)carve(4096 * 4);  // zeroed by the memset node
  // contiguous region zeroed inside k_score: leaf|summary|meta
  char* zbase = ws + off;
  unsigned* leaf = (unsigned*)carve((size_t)(1 << 20) * 4);  // 4 MB
  unsigned* summary = (unsigned*)carve(4096 * 4);
  unsigned* meta = (unsigned*)carve(8 * 4);  // [1]=ticket
  size_t zbytes = (size_t)((ws + off) - zbase);
  int nz4 = (int)(zbytes / 16);
  ull* sup = (ull*)carve((size_t)NS * NW * 8);
  (void)ws_size;
  (void)n_in;
  (void)out_size;

  hipMemsetAsync(hist0, 0, 4096 * 4, stream);
  k_score<<<1024, 256, 0, stream>>>(cla, keys, hist0, (uint4*)zbase, nz4, A);
  k_hist1<<<512, 256, 0, stream>>>(keys, hist0, leaf, summary, A);
  k_supdec<<<16, 1024, 0, stream>>>(cla, reg, anchors, hp, wp, keys, hist0, leaf,
                                    summary, sup, meta, out, A);
}

// Round 6
// 328.351 us; speedup vs baseline: 1.2735x; 1.2735x over previous
//
#include <hip/hip_runtime.h>
#include <stdint.h>

// ---------------------------------------------------------------------------
// EfficientDet post-process, multi-dispatch (grid.sync() proved ~100us/sync on
// 8-XCD gfx950 -> kernel-boundary sync instead). 4 nodes:
//   memset(hist0 16KB) ->
//   k_score   : zero 4MB aux region + per-anchor max over 80 cls + 12b hist0
//   k_hist1   : scan(hist0)->d0; 2^20-bin leaf hist + 4096-group summary
//   k_supdec  : 64 blocks. Phase A (all 64): threshold + PARALLEL atomic
//               gather (round-4 k_gather at full TLP). Ticket#1: blocks>=16
//               exit; blocks 0..15 spin till all 64 done (co-residency
//               guaranteed: 64 blocks x 16 waves on 256 CUs). Phase B
//               (16 blocks): decode + key-order IoU bitmatrix + ticket#2 +
//               last-block parallel-fixpoint NMS + rank output.
// Round-5 lesson: 16-block redundant gather was HBM-latency-bound (176us,
// 49GB/s, 108 serialized loads/thread). Fusion only wins if the fused phase
// keeps the donor kernel's parallelism -> gather runs on all 64 blocks.
// ---------------------------------------------------------------------------

#define NK 1000
#define CAP 2048
#define NS 1024   // NMS slot count (>= 1000 + exact-float-tie margin)
#define NCLS 80
#define NW 16
#define NB 64     // k_supdec grid (all co-resident -> spin-safe)
#define IOB 16    // blocks doing phase B (IoU)
typedef unsigned long long ull;

static inline __device__ unsigned fkey(float f) {
  unsigned u = __float_as_uint(f);
  return (u & 0x80000000u) ? ~u : (u | 0x80000000u);
}
static inline __device__ float fkey_inv(unsigned k) {
  unsigned u = (k & 0x80000000u) ? (k & 0x7fffffffu) : ~k;
  return __uint_as_float(u);
}

// Redundant per-block selection scan (first 256 threads participate; blockDim
// must be >= 256). Finds largest digit with suffix-count >= k and the count
// strictly above that digit. Pure function of gh -> identical across blocks.
__device__ __forceinline__ void scan_select(const unsigned* __restrict__ gh, int nbins,
                                            unsigned k, unsigned* s_sum, unsigned* s_res,
                                            unsigned& digit, unsigned& cum_above) {
  int t = threadIdx.x;
  int chunk = nbins >> 8;
  if (chunk < 1) chunk = 1;
  int base = t * chunk;
  unsigned s = 0;
  if (t < 256)
    for (int b = 0; b < chunk; ++b) s += gh[base + b];
  if (t < 256) s_sum[t] = s;
  __syncthreads();
  if (t < 256) {
    unsigned ca = 0;
    for (int u = t + 1; u < 256; ++u) ca += s_sum[u];
    if (ca < k && ca + s >= k) {  // exactly one thread
      unsigned cum = ca;
      for (int b = chunk - 1; b >= 0; --b) {
        unsigned c = gh[base + b];
        if (cum + c >= k) { s_res[0] = (unsigned)(base + b); s_res[1] = cum; break; }
        cum += c;
      }
    }
  }
  __syncthreads();
  digit = s_res[0];
  cum_above = s_res[1];
  __syncthreads();
}

// ---- K1: zero aux region + score + key + top-12-bit histogram --------------
__global__ __launch_bounds__(256) void k_score(const float* __restrict__ cla,
                                               unsigned* __restrict__ keys,
                                               unsigned* __restrict__ hist0,
                                               uint4* __restrict__ zreg, int nz4,
                                               int A) {
  __shared__ unsigned lh[4096];
  int t = threadIdx.x;
  // Zero leaf hist (4MB) + summary + meta + cand_keys (consumed only by later
  // dispatches, so no intra-kernel ordering needed). Replaces a memset node.
  {
    const uint4 z = make_uint4(0u, 0u, 0u, 0u);
    int stride = gridDim.x * 256;
    for (int i = blockIdx.x * 256 + t; i < nz4; i += stride) zreg[i] = z;
  }
  for (int i = t; i < 4096; i += 256) lh[i] = 0u;
  __syncthreads();
  const int lane = t & 63, wib = t >> 6;
  const int gwave = blockIdx.x * 4 + wib, nwaves = gridDim.x * 4;
  const int q = lane >> 2, sub = lane & 3;  // 4 lanes per 320B anchor row
  const int ntask = (A + 15) >> 4;
  for (int task = gwave; task < ntask; task += nwaves) {
    int a = task * 16 + q;
    float m = -3.402823466e38f;
    if (a < A) {
      const float4* p = (const float4*)(cla + (size_t)a * NCLS);
#pragma unroll
      for (int j = 0; j < 5; ++j) {
        float4 v = p[sub + j * 4];
        m = fmaxf(m, fmaxf(fmaxf(v.x, v.y), fmaxf(v.z, v.w)));
      }
    }
    m = fmaxf(m, __shfl_xor(m, 1, 64));
    m = fmaxf(m, __shfl_xor(m, 2, 64));
    if (sub == 0 && a < A) {
      unsigned key = fkey(m);
      keys[a] = key;
      atomicAdd(&lh[key >> 20], 1u);
    }
  }
  __syncthreads();
  for (int i = t; i < 4096; i += 256) {
    unsigned c = lh[i];
    if (c) atomicAdd(&hist0[i], c);
  }
}

// ---- K2: 2^20-bin leaf histogram + 4096-group summary ----------------------
__global__ __launch_bounds__(256) void k_hist1(const unsigned* __restrict__ keys,
                                               const unsigned* __restrict__ hist0,
                                               unsigned* __restrict__ leaf,
                                               unsigned* __restrict__ summary, int A) {
  __shared__ unsigned lh[4096];
  __shared__ unsigned s_sum[256];
  __shared__ unsigned s_res[2];
  int t = threadIdx.x;
  unsigned d0, ca;
  scan_select(hist0, 4096, NK, s_sum, s_res, d0, ca);
  for (int i = t; i < 4096; i += 256) lh[i] = 0u;
  __syncthreads();
  int tid = blockIdx.x * 256 + t, nthr = gridDim.x * 256;
  for (int a = tid; a < A; a += nthr) {
    unsigned key = keys[a];
    if ((key >> 20) == d0) {
      unsigned low = key & 0xFFFFFu;
      atomicAdd(&leaf[low], 1u);       // scattered over 1M bins -> low contention
      atomicAdd(&lh[low >> 8], 1u);    // LDS-aggregated group summary
    }
  }
  __syncthreads();
  for (int i = t; i < 4096; i += 256) {
    unsigned c = lh[i];
    if (c) atomicAdd(&summary[i], c);
  }
}

// ---- K3: parallel gather + spin-join + decode + IoU + fixpoint + output ----
__global__ __launch_bounds__(1024) void k_supdec(
    const float* __restrict__ cla, const float* __restrict__ reg,
    const float* __restrict__ anchors, const int* __restrict__ hp,
    const int* __restrict__ wp, const unsigned* __restrict__ keys,
    const unsigned* __restrict__ hist0, const unsigned* __restrict__ leaf,
    const unsigned* __restrict__ summary, ull* __restrict__ cand_keys,
    ull* __restrict__ sup, unsigned* __restrict__ meta,
    float* __restrict__ out, int A) {
  __shared__ unsigned s_sum[256];
  __shared__ unsigned s_res[2];
  __shared__ ull lbuf[1024];
  __shared__ unsigned lcnt, gbase;
  __shared__ ull ckl[NS];
  __shared__ float4 bx[NS];
  __shared__ float ar[NS];
  __shared__ unsigned keptm[32], notm[32];  // NS-bit kept / decided-not masks
  __shared__ int s_chg;
  __shared__ int s_last;
  int t = threadIdx.x;
  // ---- exact 32-bit threshold (pure function of hists -> identical/block)
  unsigned k_rem = NK, d0, g, b, ca;
  scan_select(hist0, 4096, k_rem, s_sum, s_res, d0, ca);
  k_rem -= ca;
  scan_select(summary, 4096, k_rem, s_sum, s_res, g, ca);
  k_rem -= ca;
  scan_select(leaf + (size_t)g * 256, 256, k_rem, s_sum, s_res, b, ca);
  const unsigned T = (d0 << 20) | (g << 8) | b;  // 1000th-largest key (exact)
  // ---- phase A (ALL 64 blocks): atomic-append gather at full TLP.
  // Order nondeterminism is harmless: NMS consumes unsorted slots via the
  // 64-bit ck total order; output is placed by rank.
  if (t == 0) lcnt = 0u;
  __syncthreads();
  {
    int gtid = blockIdx.x * 1024 + t, nthr = NB * 1024;
    int nv = A >> 2;
    const uint4* k4 = (const uint4*)keys;
    for (int i = gtid; i < nv; i += nthr) {
      uint4 v = k4[i];
      if (v.x >= T) { unsigned p = atomicAdd(&lcnt, 1u); if (p < 1024) lbuf[p] = ((ull)v.x << 32) | (ull)(~(unsigned)(4 * i)); }
      if (v.y >= T) { unsigned p = atomicAdd(&lcnt, 1u); if (p < 1024) lbuf[p] = ((ull)v.y << 32) | (ull)(~(unsigned)(4 * i + 1)); }
      if (v.z >= T) { unsigned p = atomicAdd(&lcnt, 1u); if (p < 1024) lbuf[p] = ((ull)v.z << 32) | (ull)(~(unsigned)(4 * i + 2)); }
      if (v.w >= T) { unsigned p = atomicAdd(&lcnt, 1u); if (p < 1024) lbuf[p] = ((ull)v.w << 32) | (ull)(~(unsigned)(4 * i + 3)); }
    }
    for (int a2 = (nv << 2) + gtid; a2 < A; a2 += nthr) {  // tail (A%4)
      unsigned kk = keys[a2];
      if (kk >= T) { unsigned p = atomicAdd(&lcnt, 1u); if (p < 1024) lbuf[p] = ((ull)kk << 32) | (ull)(~(unsigned)a2); }
    }
  }
  __syncthreads();
  if (t == 0) gbase = (lcnt > 0) ? atomicAdd(&meta[0], lcnt) : 0u;
  __syncthreads();
  {
    unsigned n = lcnt < 1024u ? lcnt : 1024u;
    for (unsigned i = t; i < n; i += 1024) {
      unsigned pos = gbase + i;
      if (pos < CAP) cand_keys[pos] = lbuf[i];
    }
  }
  // ---- ticket #1: release cand_keys, count arrivals
  __threadfence();
  __syncthreads();
  if (t == 0)
    __hip_atomic_fetch_add(&meta[1], 1u, __ATOMIC_ACQ_REL, __HIP_MEMORY_SCOPE_AGENT);
  __syncthreads();
  if (blockIdx.x >= IOB) return;  // uniform exit; 16 survivors spin-join
  // spin until all NB blocks finished phase A. Deadlock-free: NB=64 blocks x
  // 16 waves all co-resident on 256 CUs (44 VGPR), so arrivals are guaranteed.
  if (t == 0) {
    while (__hip_atomic_load(&meta[1], __ATOMIC_RELAXED, __HIP_MEMORY_SCOPE_AGENT) <
           (unsigned)NB)
      __builtin_amdgcn_s_sleep(8);
  }
  __syncthreads();
  __threadfence();  // acquire: other blocks' cand_keys now visible
  // ---- phase B (16 blocks): identical to round-4 proven pipeline.
  ckl[t] = __hip_atomic_load(&cand_keys[t], __ATOMIC_RELAXED,
                             __HIP_MEMORY_SCOPE_AGENT);
  __syncthreads();
  // decode: 1 slot per thread
  ull ck = ckl[t];
  float score = 0.0f;
  bool valid = false;
  if (ck != 0ull) {
    unsigned a = ~(unsigned)(ck & 0xFFFFFFFFull);
    score = fkey_inv((unsigned)(ck >> 32));
    float W1 = (float)wp[0] - 1.0f;
    float H1 = (float)hp[0] - 1.0f;
    float4 dd = ((const float4*)reg)[a];
    float4 an = ((const float4*)anchors)[a];
    float wa = an.z - an.x, haa = an.w - an.y;
    float cxa = an.x + 0.5f * wa, cya = an.y + 0.5f * haa;
    float cx = cxa + dd.x * wa, cy = cya + dd.y * haa;
    float w = wa * expf(dd.z), h = haa * expf(dd.w);
    float x1 = fminf(fmaxf(cx - 0.5f * w, 0.0f), W1);
    float y1 = fminf(fmaxf(cy - 0.5f * h, 0.0f), H1);
    float x2 = fminf(fmaxf(cx + 0.5f * w, 0.0f), W1);
    float y2 = fminf(fmaxf(cy + 0.5f * h, 0.0f), H1);
    bx[t] = make_float4(x1, y1, x2, y2);
    ar[t] = fmaxf(x2 - x1, 0.0f) * fmaxf(y2 - y1, 0.0f);
    valid = (score > 0.5f);
  } else {
    bx[t] = make_float4(0.f, 0.f, 0.f, 0.f);
    ar[t] = 0.0f;
  }
  __syncthreads();
  // IoU + key-order suppression word: 16 blocks x 1024 thr = NS*NW pairs.
  // j staggered by w -> distinct bank groups across the 16 w-lanes.
  {
    int gidx = blockIdx.x * 1024 + t;
    int i = gidx >> 4, w = gidx & 15;
    ull cki = ckl[i];
    float4 bi = bx[i];
    float ai = ar[i];
    ull bits = 0ull;
    int j0 = w * 64;
#pragma unroll 4
    for (int s = 0; s < 64; ++s) {
      int jj = (s + w) & 63;
      int j = j0 + jj;
      ull ckj = ckl[j];
      if (ckj > cki) {  // j precedes i in greedy order
        float4 bj = bx[j];
        float xx1 = fmaxf(bi.x, bj.x), yy1 = fmaxf(bi.y, bj.y);
        float xx2 = fminf(bi.z, bj.z), yy2 = fminf(bi.w, bj.w);
        float inter = fmaxf(xx2 - xx1, 0.0f) * fmaxf(yy2 - yy1, 0.0f);
        float uni = ai + ar[j] - inter;
        float iou = inter / fmaxf(uni, 1e-8f);
        if (iou > 0.5f) bits |= (1ull << jj);
      }
    }
    sup[(size_t)i * NW + w] = bits;
  }
  // ---- ticket #2: release sup rows, last of the 16 resolves
  __threadfence();
  __syncthreads();
  if (t == 0) {
    unsigned done = __hip_atomic_fetch_add(&meta[2], 1u, __ATOMIC_ACQ_REL,
                                           __HIP_MEMORY_SCOPE_AGENT);
    s_last = (done == IOB - 1) ? 1 : 0;
    s_chg = 0;
  }
  __syncthreads();
  if (!s_last) return;
  // ---- last block: rank (output placement + top-NK gate). LDS broadcast.
  unsigned rnk = 0;
  for (int j = 0; j < NS; ++j) rnk += (ckl[j] > ck) ? 1u : 0u;
  if (t < 32) { keptm[t] = 0u; notm[t] = 0u; }
  bool active = (ck != 0ull) && (rnk < NK);
  bool decided = (!active) || (!valid);
  ull rw[NW];  // fully unrolled static indexing only -> registers, not scratch
#pragma unroll
  for (int w = 0; w < NW; ++w)
    rw[w] = __hip_atomic_load(&sup[(size_t)t * NW + w], __ATOMIC_RELAXED,
                              __HIP_MEMORY_SCOPE_AGENT);
  __syncthreads();
  // pad slots, rank>=NK ties, and invalid-score rows are force-dropped here,
  // so they can never suppress (not in keptm) and never stall pot (in notm).
  if (decided) atomicOr(&notm[t >> 5], 1u << (t & 31));
  __syncthreads();
  // monotone-fixpoint greedy NMS (order = ck desc; relation pre-masked by
  // ckj>cki in the bitmatrix, so no triangle masking needed here).
  for (int round = 0; round < NS; ++round) {
    if (!decided) {
      ull hit = 0ull, pot = 0ull;
#pragma unroll
      for (int w = 0; w < NW; ++w) {
        ull km = ((ull)keptm[2 * w + 1] << 32) | (ull)keptm[2 * w];
        ull nm = ((ull)notm[2 * w + 1] << 32) | (ull)notm[2 * w];
        hit |= rw[w] & km;
        pot |= rw[w] & ~(km | nm);
      }
      if (hit) {
        decided = true;
        atomicOr(&notm[t >> 5], 1u << (t & 31));
        s_chg = 1;  // benign race: all writers store 1
      } else if (!pot) {
        decided = true;
        atomicOr(&keptm[t >> 5], 1u << (t & 31));
        s_chg = 1;
      }
    }
    __syncthreads();
    if (s_chg == 0) break;
    __syncthreads();
    if (t == 0) s_chg = 0;
    __syncthreads();
  }
  // ---- argmax class (kept rows only) + output write at rank position
  if (active) {
    bool kp = (keptm[t >> 5] >> (t & 31)) & 1u;
    int ci = 0;
    if (kp) {
      unsigned a = ~(unsigned)(ck & 0xFFFFFFFFull);
      const float* row = cla + (size_t)a * NCLS;
      float m = -3.402823466e38f;
#pragma unroll
      for (int j = 0; j < NCLS; ++j) {
        float v = row[j];
        if (v > m) { m = v; ci = j; }
      }
    }
    out[rnk] = kp ? score : 0.0f;
    out[NK + rnk] = kp ? (float)ci : -1.0f;  // int output read as float
    float4 bo = bx[t];
    ((float4*)(out + 2 * NK))[rnk] = kp ? bo : make_float4(0.f, 0.f, 0.f, 0.f);
  }
}

extern "C" void kernel_launch(void* const* d_in, const int* in_sizes, int n_in,
                              void* d_out, int out_size, void* d_ws, size_t ws_size,
                              hipStream_t stream) {
  const float* cla = (const float*)d_in[0];
  const float* reg = (const float*)d_in[1];
  const float* anchors = (const float*)d_in[2];
  const int* hp = (const int*)d_in[3];
  const int* wp = (const int*)d_in[4];
  float* out = (float*)d_out;
  int A = in_sizes[2] / 4;  // 441936

  char* ws = (char*)d_ws;
  size_t off = 0;
  auto carve = [&](size_t bytes) -> void* {
    void* p = ws + off;
    off += bytes;
    off = (off + 255) & ~(size_t)255;
    return p;
  };
  unsigned* keys = (unsigned*)carve((size_t)A * 4);
  unsigned* hist0 = (unsigned*)carve(4096 * 4);  // zeroed by the memset node
  // contiguous region zeroed inside k_score: leaf|summary|meta|cand_keys
  char* zbase = ws + off;
  unsigned* leaf = (unsigned*)carve((size_t)(1 << 20) * 4);  // 4 MB
  unsigned* summary = (unsigned*)carve(4096 * 4);
  unsigned* meta = (unsigned*)carve(8 * 4);  // [0]=count [1]=ticketA [2]=ticketB
  ull* cand_keys = (ull*)carve(CAP * 8);
  size_t zbytes = (size_t)((ws + off) - zbase);
  int nz4 = (int)(zbytes / 16);
  ull* sup = (ull*)carve((size_t)NS * NW * 8);
  (void)ws_size;
  (void)n_in;
  (void)out_size;

  hipMemsetAsync(hist0, 0, 4096 * 4, stream);
  k_score<<<1024, 256, 0, stream>>>(cla, keys, hist0, (uint4*)zbase, nz4, A);
  k_hist1<<<512, 256, 0, stream>>>(keys, hist0, leaf, summary, A);
  k_supdec<<<NB, 1024, 0, stream>>>(cla, reg, anchors, hp, wp, keys, hist0, leaf,
                                    summary, cand_keys, sup, meta, out, A);
}

// Round 8
// 323.431 us; speedup vs baseline: 1.2928x; 1.0152x over previous
//
#include <hip/hip_runtime.h>
#include <stdint.h>

// ---------------------------------------------------------------------------
// EfficientDet post-process, multi-dispatch (grid.sync() proved ~100us/sync on
// 8-XCD gfx950 -> kernel-boundary sync instead). 4 nodes:
//   memset(hist0 16KB) ->
//   k_score   : zero 4MB aux region + per-anchor max over 80 cls + 12b hist0
//   k_hist1   : scan(hist0)->d0; 2^20-bin leaf hist + 4096-group summary
//   k_supdec  : 64 blocks. Phase A (all 64): threshold + PARALLEL atomic
//               gather. Ticket#1: blocks>=16 exit; 16 survivors spin-join.
//               Phase B (16 blocks): decode + key-order IoU bitmatrix WITH
//               FUSED RANK (shfl-reduced, written to rank_g) + ticket#2 +
//               last-block parallel-fixpoint NMS + rank-placed output.
// Round-6 lesson: k_supdec's 98.8us was a deterministic single-CU tail —
// the last-block 1024x1024 LDS rank loop (~40us on one CU). Rank is now a
// free byproduct of the 16-block IoU pass (ckj>cki count + 4 shfl_xor).
// Round-7 lesson: a "2-barrier" fixpoint loop raced the break-decision read
// against thread 0's s_chg reset -> divergent break -> barrier hang. The
// 3-barrier loop (writes pre-B1, reads B1..B2, reset post-B2) is required.
// ---------------------------------------------------------------------------

#define NK 1000
#define CAP 2048
#define NS 1024   // NMS slot count (>= 1000 + exact-float-tie margin)
#define NCLS 80
#define NW 16
#define NB 64     // k_supdec grid (all co-resident -> spin-safe)
#define IOB 16    // blocks doing phase B (IoU)
typedef unsigned long long ull;

static inline __device__ unsigned fkey(float f) {
  unsigned u = __float_as_uint(f);
  return (u & 0x80000000u) ? ~u : (u | 0x80000000u);
}
static inline __device__ float fkey_inv(unsigned k) {
  unsigned u = (k & 0x80000000u) ? (k & 0x7fffffffu) : ~k;
  return __uint_as_float(u);
}

// Redundant per-block selection scan (first 256 threads participate; blockDim
// must be >= 256). Finds largest digit with suffix-count >= k and the count
// strictly above that digit. Pure function of gh -> identical across blocks.
__device__ __forceinline__ void scan_select(const unsigned* __restrict__ gh, int nbins,
                                            unsigned k, unsigned* s_sum, unsigned* s_res,
                                            unsigned& digit, unsigned& cum_above) {
  int t = threadIdx.x;
  int chunk = nbins >> 8;
  if (chunk < 1) chunk = 1;
  int base = t * chunk;
  unsigned s = 0;
  if (t < 256)
    for (int b = 0; b < chunk; ++b) s += gh[base + b];
  if (t < 256) s_sum[t] = s;
  __syncthreads();
  if (t < 256) {
    unsigned ca = 0;
    for (int u = t + 1; u < 256; ++u) ca += s_sum[u];
    if (ca < k && ca + s >= k) {  // exactly one thread
      unsigned cum = ca;
      for (int b = chunk - 1; b >= 0; --b) {
        unsigned c = gh[base + b];
        if (cum + c >= k) { s_res[0] = (unsigned)(base + b); s_res[1] = cum; break; }
        cum += c;
      }
    }
  }
  __syncthreads();
  digit = s_res[0];
  cum_above = s_res[1];
  __syncthreads();
}

// ---- K1: zero aux region + score + key + top-12-bit histogram --------------
__global__ __launch_bounds__(256) void k_score(const float* __restrict__ cla,
                                               unsigned* __restrict__ keys,
                                               unsigned* __restrict__ hist0,
                                               uint4* __restrict__ zreg, int nz4,
                                               int A) {
  __shared__ unsigned lh[4096];
  int t = threadIdx.x;
  // Zero leaf hist (4MB) + summary + meta + cand_keys (consumed only by later
  // dispatches, so no intra-kernel ordering needed). Replaces a memset node.
  {
    const uint4 z = make_uint4(0u, 0u, 0u, 0u);
    int stride = gridDim.x * 256;
    for (int i = blockIdx.x * 256 + t; i < nz4; i += stride) zreg[i] = z;
  }
  for (int i = t; i < 4096; i += 256) lh[i] = 0u;
  __syncthreads();
  const int lane = t & 63, wib = t >> 6;
  const int gwave = blockIdx.x * 4 + wib, nwaves = gridDim.x * 4;
  const int q = lane >> 2, sub = lane & 3;  // 4 lanes per 320B anchor row
  const int ntask = (A + 15) >> 4;
  for (int task = gwave; task < ntask; task += nwaves) {
    int a = task * 16 + q;
    float m = -3.402823466e38f;
    if (a < A) {
      const float4* p = (const float4*)(cla + (size_t)a * NCLS);
#pragma unroll
      for (int j = 0; j < 5; ++j) {
        float4 v = p[sub + j * 4];
        m = fmaxf(m, fmaxf(fmaxf(v.x, v.y), fmaxf(v.z, v.w)));
      }
    }
    m = fmaxf(m, __shfl_xor(m, 1, 64));
    m = fmaxf(m, __shfl_xor(m, 2, 64));
    if (sub == 0 && a < A) {
      unsigned key = fkey(m);
      keys[a] = key;
      atomicAdd(&lh[key >> 20], 1u);
    }
  }
  __syncthreads();
  for (int i = t; i < 4096; i += 256) {
    unsigned c = lh[i];
    if (c) atomicAdd(&hist0[i], c);
  }
}

// ---- K2: 2^20-bin leaf histogram + 4096-group summary ----------------------
__global__ __launch_bounds__(256) void k_hist1(const unsigned* __restrict__ keys,
                                               const unsigned* __restrict__ hist0,
                                               unsigned* __restrict__ leaf,
                                               unsigned* __restrict__ summary, int A) {
  __shared__ unsigned lh[4096];
  __shared__ unsigned s_sum[256];
  __shared__ unsigned s_res[2];
  int t = threadIdx.x;
  unsigned d0, ca;
  scan_select(hist0, 4096, NK, s_sum, s_res, d0, ca);
  for (int i = t; i < 4096; i += 256) lh[i] = 0u;
  __syncthreads();
  int tid = blockIdx.x * 256 + t, nthr = gridDim.x * 256;
  for (int a = tid; a < A; a += nthr) {
    unsigned key = keys[a];
    if ((key >> 20) == d0) {
      unsigned low = key & 0xFFFFFu;
      atomicAdd(&leaf[low], 1u);       // scattered over 1M bins -> low contention
      atomicAdd(&lh[low >> 8], 1u);    // LDS-aggregated group summary
    }
  }
  __syncthreads();
  for (int i = t; i < 4096; i += 256) {
    unsigned c = lh[i];
    if (c) atomicAdd(&summary[i], c);
  }
}

// ---- K3: parallel gather + spin-join + decode + IoU(+rank) + fixpoint ------
__global__ __launch_bounds__(1024) void k_supdec(
    const float* __restrict__ cla, const float* __restrict__ reg,
    const float* __restrict__ anchors, const int* __restrict__ hp,
    const int* __restrict__ wp, const unsigned* __restrict__ keys,
    const unsigned* __restrict__ hist0, const unsigned* __restrict__ leaf,
    const unsigned* __restrict__ summary, ull* __restrict__ cand_keys,
    ull* __restrict__ sup, unsigned* __restrict__ rank_g,
    unsigned* __restrict__ meta, float* __restrict__ out, int A) {
  __shared__ unsigned s_sum[256];
  __shared__ unsigned s_res[2];
  __shared__ ull lbuf[1024];
  __shared__ unsigned lcnt, gbase;
  __shared__ ull ckl[NS];
  __shared__ float4 bx[NS];
  __shared__ float ar[NS];
  __shared__ unsigned keptm[32], notm[32];  // NS-bit kept / decided-not masks
  __shared__ int s_chg;
  __shared__ int s_last;
  int t = threadIdx.x;
  // ---- exact 32-bit threshold (pure function of hists -> identical/block)
  unsigned k_rem = NK, d0, g, b, ca;
  scan_select(hist0, 4096, k_rem, s_sum, s_res, d0, ca);
  k_rem -= ca;
  scan_select(summary, 4096, k_rem, s_sum, s_res, g, ca);
  k_rem -= ca;
  scan_select(leaf + (size_t)g * 256, 256, k_rem, s_sum, s_res, b, ca);
  const unsigned T = (d0 << 20) | (g << 8) | b;  // 1000th-largest key (exact)
  // ---- phase A (ALL 64 blocks): atomic-append gather at full TLP.
  // Order nondeterminism is harmless: NMS consumes unsorted slots via the
  // 64-bit ck total order; output is placed by rank.
  if (t == 0) lcnt = 0u;
  __syncthreads();
  {
    int gtid = blockIdx.x * 1024 + t, nthr = NB * 1024;
    int nv = A >> 2;
    const uint4* k4 = (const uint4*)keys;
    for (int i = gtid; i < nv; i += nthr) {
      uint4 v = k4[i];
      if (v.x >= T) { unsigned p = atomicAdd(&lcnt, 1u); if (p < 1024) lbuf[p] = ((ull)v.x << 32) | (ull)(~(unsigned)(4 * i)); }
      if (v.y >= T) { unsigned p = atomicAdd(&lcnt, 1u); if (p < 1024) lbuf[p] = ((ull)v.y << 32) | (ull)(~(unsigned)(4 * i + 1)); }
      if (v.z >= T) { unsigned p = atomicAdd(&lcnt, 1u); if (p < 1024) lbuf[p] = ((ull)v.z << 32) | (ull)(~(unsigned)(4 * i + 2)); }
      if (v.w >= T) { unsigned p = atomicAdd(&lcnt, 1u); if (p < 1024) lbuf[p] = ((ull)v.w << 32) | (ull)(~(unsigned)(4 * i + 3)); }
    }
    for (int a2 = (nv << 2) + gtid; a2 < A; a2 += nthr) {  // tail (A%4)
      unsigned kk = keys[a2];
      if (kk >= T) { unsigned p = atomicAdd(&lcnt, 1u); if (p < 1024) lbuf[p] = ((ull)kk << 32) | (ull)(~(unsigned)a2); }
    }
  }
  __syncthreads();
  if (t == 0) gbase = (lcnt > 0) ? atomicAdd(&meta[0], lcnt) : 0u;
  __syncthreads();
  {
    unsigned n = lcnt < 1024u ? lcnt : 1024u;
    for (unsigned i = t; i < n; i += 1024) {
      unsigned pos = gbase + i;
      if (pos < CAP) cand_keys[pos] = lbuf[i];
    }
  }
  // ---- ticket #1: release cand_keys, count arrivals
  __threadfence();
  __syncthreads();
  if (t == 0)
    __hip_atomic_fetch_add(&meta[1], 1u, __ATOMIC_ACQ_REL, __HIP_MEMORY_SCOPE_AGENT);
  __syncthreads();
  if (blockIdx.x >= IOB) return;  // uniform exit; 16 survivors spin-join
  // spin until all NB blocks finished phase A. Deadlock-free: NB=64 blocks x
  // 16 waves all co-resident on 256 CUs (44 VGPR), so arrivals are guaranteed.
  if (t == 0) {
    while (__hip_atomic_load(&meta[1], __ATOMIC_RELAXED, __HIP_MEMORY_SCOPE_AGENT) <
           (unsigned)NB)
      __builtin_amdgcn_s_sleep(8);
  }
  __syncthreads();
  __threadfence();  // acquire: other blocks' cand_keys now visible
  // ---- phase B (16 blocks): decode 1 slot/thread
  ckl[t] = __hip_atomic_load(&cand_keys[t], __ATOMIC_RELAXED,
                             __HIP_MEMORY_SCOPE_AGENT);
  __syncthreads();
  ull ck = ckl[t];
  float score = 0.0f;
  bool valid = false;
  if (ck != 0ull) {
    unsigned a = ~(unsigned)(ck & 0xFFFFFFFFull);
    score = fkey_inv((unsigned)(ck >> 32));
    float W1 = (float)wp[0] - 1.0f;
    float H1 = (float)hp[0] - 1.0f;
    float4 dd = ((const float4*)reg)[a];
    float4 an = ((const float4*)anchors)[a];
    float wa = an.z - an.x, haa = an.w - an.y;
    float cxa = an.x + 0.5f * wa, cya = an.y + 0.5f * haa;
    float cx = cxa + dd.x * wa, cy = cya + dd.y * haa;
    float w = wa * expf(dd.z), h = haa * expf(dd.w);
    float x1 = fminf(fmaxf(cx - 0.5f * w, 0.0f), W1);
    float y1 = fminf(fmaxf(cy - 0.5f * h, 0.0f), H1);
    float x2 = fminf(fmaxf(cx + 0.5f * w, 0.0f), W1);
    float y2 = fminf(fmaxf(cy + 0.5f * h, 0.0f), H1);
    bx[t] = make_float4(x1, y1, x2, y2);
    ar[t] = fmaxf(x2 - x1, 0.0f) * fmaxf(y2 - y1, 0.0f);
    valid = (score > 0.5f);
  } else {
    bx[t] = make_float4(0.f, 0.f, 0.f, 0.f);
    ar[t] = 0.0f;
  }
  __syncthreads();
  // ---- IoU + key-order suppression word + FUSED RANK.
  // 16 blocks x 1024 thr = NS*NW (i,w) pairs; j staggered by w -> distinct
  // bank groups across the 16 w-lanes. rank partials: the 16 (i,w) threads
  // are 16 aligned lanes of one wave -> shfl_xor reduce is free; each slot i
  // is owned by exactly one block -> rank_g fully written, no comm needed.
  {
    int gidx = blockIdx.x * 1024 + t;
    int i = gidx >> 4, w = gidx & 15;
    ull cki = ckl[i];
    float4 bi = bx[i];
    float ai = ar[i];
    ull bits = 0ull;
    unsigned rcnt = 0;
    int j0 = w * 64;
#pragma unroll 4
    for (int s = 0; s < 64; ++s) {
      int jj = (s + w) & 63;
      int j = j0 + jj;
      ull ckj = ckl[j];
      if (ckj > cki) {  // j precedes i in greedy order
        ++rcnt;
        float4 bj = bx[j];
        float xx1 = fmaxf(bi.x, bj.x), yy1 = fmaxf(bi.y, bj.y);
        float xx2 = fminf(bi.z, bj.z), yy2 = fminf(bi.w, bj.w);
        float inter = fmaxf(xx2 - xx1, 0.0f) * fmaxf(yy2 - yy1, 0.0f);
        float uni = ai + ar[j] - inter;
        float iou = inter / fmaxf(uni, 1e-8f);
        if (iou > 0.5f) bits |= (1ull << jj);
      }
    }
    sup[(size_t)i * NW + w] = bits;
    rcnt += __shfl_xor(rcnt, 1, 64);
    rcnt += __shfl_xor(rcnt, 2, 64);
    rcnt += __shfl_xor(rcnt, 4, 64);
    rcnt += __shfl_xor(rcnt, 8, 64);
    if (w == 0) rank_g[i] = rcnt;  // released by the fence below
  }
  // ---- ticket #2: release sup+rank rows, last of the 16 resolves
  __threadfence();
  __syncthreads();
  if (t == 0) {
    unsigned done = __hip_atomic_fetch_add(&meta[2], 1u, __ATOMIC_ACQ_REL,
                                           __HIP_MEMORY_SCOPE_AGENT);
    s_last = (done == IOB - 1) ? 1 : 0;
    s_chg = 0;
  }
  __syncthreads();
  if (!s_last) return;
  __threadfence();  // acquire: other blocks' sup/rank rows visible
  // ---- last block: coalesced rank load replaces the 1024x1024 LDS loop
  unsigned rnk = __hip_atomic_load(&rank_g[t], __ATOMIC_RELAXED,
                                   __HIP_MEMORY_SCOPE_AGENT);
  if (t < 32) { keptm[t] = 0u; notm[t] = 0u; }
  bool active = (ck != 0ull) && (rnk < NK);
  bool decided = (!active) || (!valid);
  ull rw[NW];  // fully unrolled static indexing only -> registers, not scratch
#pragma unroll
  for (int w = 0; w < NW; ++w)
    rw[w] = __hip_atomic_load(&sup[(size_t)t * NW + w], __ATOMIC_RELAXED,
                              __HIP_MEMORY_SCOPE_AGENT);
  __syncthreads();
  // pad slots, rank>=NK ties, and invalid-score rows are force-dropped here,
  // so they can never suppress (not in keptm) and never stall pot (in notm).
  if (decided) atomicOr(&notm[t >> 5], 1u << (t & 31));
  __syncthreads();
  // ---- monotone-fixpoint greedy NMS (order = ck desc; relation pre-masked
  // by ckj>cki in the bitmatrix). 3-barrier rounds: s_chg=1 writes pre-B1,
  // break-read in stable region B1..B2, t0 reset post-B2 (round-7 lesson).
  for (int round = 0; round < NS; ++round) {
    if (!decided) {
      ull hit = 0ull, pot = 0ull;
#pragma unroll
      for (int w = 0; w < NW; ++w) {
        ull km = ((ull)keptm[2 * w + 1] << 32) | (ull)keptm[2 * w];
        ull nm = ((ull)notm[2 * w + 1] << 32) | (ull)notm[2 * w];
        hit |= rw[w] & km;
        pot |= rw[w] & ~(km | nm);
      }
      if (hit) {
        decided = true;
        atomicOr(&notm[t >> 5], 1u << (t & 31));
        s_chg = 1;  // benign race: all writers store 1
      } else if (!pot) {
        decided = true;
        atomicOr(&keptm[t >> 5], 1u << (t & 31));
        s_chg = 1;
      }
    }
    __syncthreads();
    if (s_chg == 0) break;
    __syncthreads();
    if (t == 0) s_chg = 0;
    __syncthreads();
  }
  // ---- argmax class (kept rows only) + output write at rank position
  if (active) {
    bool kp = (keptm[t >> 5] >> (t & 31)) & 1u;
    int ci = 0;
    if (kp) {
      unsigned a = ~(unsigned)(ck & 0xFFFFFFFFull);
      const float* row = cla + (size_t)a * NCLS;
      float m = -3.402823466e38f;
#pragma unroll
      for (int j = 0; j < NCLS; ++j) {
        float v = row[j];
        if (v > m) { m = v; ci = j; }
      }
    }
    out[rnk] = kp ? score : 0.0f;
    out[NK + rnk] = kp ? (float)ci : -1.0f;  // int output read as float
    float4 bo = bx[t];
    ((float4*)(out + 2 * NK))[rnk] = kp ? bo : make_float4(0.f, 0.f, 0.f, 0.f);
  }
}

extern "C" void kernel_launch(void* const* d_in, const int* in_sizes, int n_in,
                              void* d_out, int out_size, void* d_ws, size_t ws_size,
                              hipStream_t stream) {
  const float* cla = (const float*)d_in[0];
  const float* reg = (const float*)d_in[1];
  const float* anchors = (const float*)d_in[2];
  const int* hp = (const int*)d_in[3];
  const int* wp = (const int*)d_in[4];
  float* out = (float*)d_out;
  int A = in_sizes[2] / 4;  // 441936

  char* ws = (char*)d_ws;
  size_t off = 0;
  auto carve = [&](size_t bytes) -> void* {
    void* p = ws + off;
    off += bytes;
    off = (off + 255) & ~(size_t)255;
    return p;
  };
  unsigned* keys = (unsigned*)carve((size_t)A * 4);
  unsigned* hist0 = (unsigned*)carve(4096 * 4);  // zeroed by the memset node
  // contiguous region zeroed inside k_score: leaf|summary|meta|cand_keys
  char* zbase = ws + off;
  unsigned* leaf = (unsigned*)carve((size_t)(1 << 20) * 4);  // 4 MB
  unsigned* summary = (unsigned*)carve(4096 * 4);
  unsigned* meta = (unsigned*)carve(8 * 4);  // [0]=count [1]=ticketA [2]=ticketB
  ull* cand_keys = (ull*)carve(CAP * 8);
  size_t zbytes = (size_t)((ws + off) - zbase);
  int nz4 = (int)(zbytes / 16);
  ull* sup = (ull*)carve((size_t)NS * NW * 8);
  unsigned* rank_g = (unsigned*)carve(NS * 4);  // fully written by phase B
  (void)ws_size;
  (void)n_in;
  (void)out_size;

  hipMemsetAsync(hist0, 0, 4096 * 4, stream);
  k_score<<<1024, 256, 0, stream>>>(cla, keys, hist0, (uint4*)zbase, nz4, A);
  k_hist1<<<512, 256, 0, stream>>>(keys, hist0, leaf, summary, A);
  k_supdec<<<NB, 1024, 0, stream>>>(cla, reg, anchors, hp, wp, keys, hist0, leaf,
                                    summary, cand_keys, sup, rank_g, meta, out, A);
}

// Round 9
// 307.509 us; speedup vs baseline: 1.3598x; 1.0518x over previous
//
#include <hip/hip_runtime.h>
#include <stdint.h>

// ---------------------------------------------------------------------------
// EfficientDet post-process, multi-dispatch (grid.sync() proved ~100us/sync on
// 8-XCD gfx950 -> kernel-boundary sync instead). 5 nodes (round-4 structure,
// the measured-best sync topology: in-kernel spin-joins cost ~25-30us MORE
// than a kernel boundary on this part — rounds 6/8 evidence):
//   memset(hist0 16KB) ->
//   k_score   : zero 4MB aux region + per-anchor max over 80 cls + 12b hist0
//   k_hist1   : scan(hist0)->d0; 2^20-bin leaf hist + 4096-group summary
//   k_gather  : scans -> exact 32b threshold T, full-TLP atomic gather
//   k_supdec  : decode + key-order IoU bitmatrix WITH FUSED RANK (shfl-
//               reduced -> rank_g) + ticket + last-block fixpoint NMS + output
// Round-8 lesson: fused rank (vs last-block 1024x1024 LDS rank loop) is worth
// ~5-8us; spin-join fusion is a net loss. This kernel = round-4 + fused rank.
// ---------------------------------------------------------------------------

#define NK 1000
#define CAP 2048
#define NS 1024   // NMS slot count (>= 1000 + exact-float-tie margin)
#define NCLS 80
#define NW 16
typedef unsigned long long ull;

static inline __device__ unsigned fkey(float f) {
  unsigned u = __float_as_uint(f);
  return (u & 0x80000000u) ? ~u : (u | 0x80000000u);
}
static inline __device__ float fkey_inv(unsigned k) {
  unsigned u = (k & 0x80000000u) ? (k & 0x7fffffffu) : ~k;
  return __uint_as_float(u);
}

// Redundant per-block selection scan (first 256 threads participate; blockDim
// must be >= 256). Finds largest digit with suffix-count >= k and the count
// strictly above that digit. Pure function of gh -> identical across blocks.
__device__ __forceinline__ void scan_select(const unsigned* __restrict__ gh, int nbins,
                                            unsigned k, unsigned* s_sum, unsigned* s_res,
                                            unsigned& digit, unsigned& cum_above) {
  int t = threadIdx.x;
  int chunk = nbins >> 8;
  if (chunk < 1) chunk = 1;
  int base = t * chunk;
  unsigned s = 0;
  if (t < 256)
    for (int b = 0; b < chunk; ++b) s += gh[base + b];
  if (t < 256) s_sum[t] = s;
  __syncthreads();
  if (t < 256) {
    unsigned ca = 0;
    for (int u = t + 1; u < 256; ++u) ca += s_sum[u];
    if (ca < k && ca + s >= k) {  // exactly one thread
      unsigned cum = ca;
      for (int b = chunk - 1; b >= 0; --b) {
        unsigned c = gh[base + b];
        if (cum + c >= k) { s_res[0] = (unsigned)(base + b); s_res[1] = cum; break; }
        cum += c;
      }
    }
  }
  __syncthreads();
  digit = s_res[0];
  cum_above = s_res[1];
  __syncthreads();
}

// ---- K1: zero aux region + score + key + top-12-bit histogram --------------
__global__ __launch_bounds__(256) void k_score(const float* __restrict__ cla,
                                               unsigned* __restrict__ keys,
                                               unsigned* __restrict__ hist0,
                                               uint4* __restrict__ zreg, int nz4,
                                               int A) {
  __shared__ unsigned lh[4096];
  int t = threadIdx.x;
  // Zero leaf hist (4MB) + summary + meta + cand_keys (consumed only by later
  // dispatches, so no intra-kernel ordering needed). Replaces a memset node.
  {
    const uint4 z = make_uint4(0u, 0u, 0u, 0u);
    int stride = gridDim.x * 256;
    for (int i = blockIdx.x * 256 + t; i < nz4; i += stride) zreg[i] = z;
  }
  for (int i = t; i < 4096; i += 256) lh[i] = 0u;
  __syncthreads();
  const int lane = t & 63, wib = t >> 6;
  const int gwave = blockIdx.x * 4 + wib, nwaves = gridDim.x * 4;
  const int q = lane >> 2, sub = lane & 3;  // 4 lanes per 320B anchor row
  const int ntask = (A + 15) >> 4;
  for (int task = gwave; task < ntask; task += nwaves) {
    int a = task * 16 + q;
    float m = -3.402823466e38f;
    if (a < A) {
      const float4* p = (const float4*)(cla + (size_t)a * NCLS);
#pragma unroll
      for (int j = 0; j < 5; ++j) {
        float4 v = p[sub + j * 4];
        m = fmaxf(m, fmaxf(fmaxf(v.x, v.y), fmaxf(v.z, v.w)));
      }
    }
    m = fmaxf(m, __shfl_xor(m, 1, 64));
    m = fmaxf(m, __shfl_xor(m, 2, 64));
    if (sub == 0 && a < A) {
      unsigned key = fkey(m);
      keys[a] = key;
      atomicAdd(&lh[key >> 20], 1u);
    }
  }
  __syncthreads();
  for (int i = t; i < 4096; i += 256) {
    unsigned c = lh[i];
    if (c) atomicAdd(&hist0[i], c);
  }
}

// ---- K2: 2^20-bin leaf histogram + 4096-group summary ----------------------
__global__ __launch_bounds__(256) void k_hist1(const unsigned* __restrict__ keys,
                                               const unsigned* __restrict__ hist0,
                                               unsigned* __restrict__ leaf,
                                               unsigned* __restrict__ summary, int A) {
  __shared__ unsigned lh[4096];
  __shared__ unsigned s_sum[256];
  __shared__ unsigned s_res[2];
  int t = threadIdx.x;
  unsigned d0, ca;
  scan_select(hist0, 4096, NK, s_sum, s_res, d0, ca);
  for (int i = t; i < 4096; i += 256) lh[i] = 0u;
  __syncthreads();
  int tid = blockIdx.x * 256 + t, nthr = gridDim.x * 256;
  for (int a = tid; a < A; a += nthr) {
    unsigned key = keys[a];
    if ((key >> 20) == d0) {
      unsigned low = key & 0xFFFFFu;
      atomicAdd(&leaf[low], 1u);       // scattered over 1M bins -> low contention
      atomicAdd(&lh[low >> 8], 1u);    // LDS-aggregated group summary
    }
  }
  __syncthreads();
  for (int i = t; i < 4096; i += 256) {
    unsigned c = lh[i];
    if (c) atomicAdd(&summary[i], c);
  }
}

// ---- K3: exact 32-bit threshold + gather (full TLP, per-block LDS agg) -----
__global__ __launch_bounds__(256) void k_gather(const unsigned* __restrict__ keys,
                                                const unsigned* __restrict__ hist0,
                                                const unsigned* __restrict__ leaf,
                                                const unsigned* __restrict__ summary,
                                                unsigned* __restrict__ meta,
                                                ull* __restrict__ cand_keys, int A) {
  __shared__ unsigned s_sum[256];
  __shared__ unsigned s_res[2];
  __shared__ ull lbuf[1024];
  __shared__ unsigned lcnt;
  __shared__ unsigned gbase;
  int t = threadIdx.x;
  unsigned k_rem = NK, d0, g, b, ca;
  scan_select(hist0, 4096, k_rem, s_sum, s_res, d0, ca);
  k_rem -= ca;
  scan_select(summary, 4096, k_rem, s_sum, s_res, g, ca);
  k_rem -= ca;
  scan_select(leaf + (size_t)g * 256, 256, k_rem, s_sum, s_res, b, ca);
  // 3-level exact threshold: d0(12)|mid(12)|low(8)
  const unsigned T = (d0 << 20) | (g << 8) | b;  // 1000th-largest key (exact)
  if (t == 0) lcnt = 0u;
  __syncthreads();
  int tid = blockIdx.x * 256 + t, nthr = gridDim.x * 256;
  for (int a = tid; a < A; a += nthr) {
    unsigned key = keys[a];
    if (key >= T) {
      unsigned pos = atomicAdd(&lcnt, 1u);
      if (pos < 1024)
        lbuf[pos] = ((ull)key << 32) | (ull)(~(unsigned)a);  // (score desc, idx asc)
    }
  }
  __syncthreads();
  if (t == 0) gbase = (lcnt > 0) ? atomicAdd(&meta[0], lcnt) : 0u;
  __syncthreads();
  unsigned n = lcnt < 1024u ? lcnt : 1024u;
  for (unsigned i = t; i < n; i += 256) {
    unsigned pos = gbase + i;
    if (pos < CAP) cand_keys[pos] = lbuf[i];
  }
}

// ---- K4: decode + key-order IoU bitmatrix (+fused rank) + fixpoint + out ---
// Slots are UNSORTED candidates (exactly top-1000 + exact-score ties, rest
// zero-key padding). Greedy order is the 64-bit ck descending order.
__global__ __launch_bounds__(1024) void k_supdec(
    const float* __restrict__ cla, const float* __restrict__ reg,
    const float* __restrict__ anchors, const int* __restrict__ hp,
    const int* __restrict__ wp, const ull* __restrict__ cand_keys,
    ull* __restrict__ sup, unsigned* __restrict__ rank_g,
    unsigned* __restrict__ meta, float* __restrict__ out) {
  __shared__ ull ckl[NS];
  __shared__ float4 bx[NS];
  __shared__ float ar[NS];
  __shared__ unsigned keptm[32], notm[32];  // NS-bit kept / decided-not masks
  __shared__ int s_chg;
  __shared__ int s_last;
  int t = threadIdx.x;
  ckl[t] = cand_keys[t];  // plain load: producer was a previous dispatch
  __syncthreads();
  // ---- decode: 1 slot per thread
  ull ck = ckl[t];
  float score = 0.0f;
  bool valid = false;
  if (ck != 0ull) {
    unsigned a = ~(unsigned)(ck & 0xFFFFFFFFull);
    score = fkey_inv((unsigned)(ck >> 32));
    float W1 = (float)wp[0] - 1.0f;
    float H1 = (float)hp[0] - 1.0f;
    float4 dd = ((const float4*)reg)[a];
    float4 an = ((const float4*)anchors)[a];
    float wa = an.z - an.x, haa = an.w - an.y;
    float cxa = an.x + 0.5f * wa, cya = an.y + 0.5f * haa;
    float cx = cxa + dd.x * wa, cy = cya + dd.y * haa;
    float w = wa * expf(dd.z), h = haa * expf(dd.w);
    float x1 = fminf(fmaxf(cx - 0.5f * w, 0.0f), W1);
    float y1 = fminf(fmaxf(cy - 0.5f * h, 0.0f), H1);
    float x2 = fminf(fmaxf(cx + 0.5f * w, 0.0f), W1);
    float y2 = fminf(fmaxf(cy + 0.5f * h, 0.0f), H1);
    bx[t] = make_float4(x1, y1, x2, y2);
    ar[t] = fmaxf(x2 - x1, 0.0f) * fmaxf(y2 - y1, 0.0f);
    valid = (score > 0.5f);
  } else {
    bx[t] = make_float4(0.f, 0.f, 0.f, 0.f);
    ar[t] = 0.0f;
  }
  __syncthreads();
  // ---- IoU + key-order suppression word + FUSED RANK.
  // 16 blocks x 1024 thr = NS*NW (i,w) pairs; j staggered by w -> distinct
  // bank groups across the 16 w-lanes (2-way conflict, free). The 16 (i,w)
  // threads of a row are 16 aligned lanes of one wave -> shfl_xor reduce of
  // the per-stripe (ckj>cki) counts is free; each slot i is owned by exactly
  // one block -> rank_g fully written, no cross-block comm.
  {
    int gidx = blockIdx.x * 1024 + t;
    int i = gidx >> 4, w = gidx & 15;
    ull cki = ckl[i];
    float4 bi = bx[i];
    float ai = ar[i];
    ull bits = 0ull;
    unsigned rcnt = 0;
    int j0 = w * 64;
#pragma unroll 4
    for (int s = 0; s < 64; ++s) {
      int jj = (s + w) & 63;
      int j = j0 + jj;
      ull ckj = ckl[j];
      if (ckj > cki) {  // j precedes i in greedy order
        ++rcnt;
        float4 bj = bx[j];
        float xx1 = fmaxf(bi.x, bj.x), yy1 = fmaxf(bi.y, bj.y);
        float xx2 = fminf(bi.z, bj.z), yy2 = fminf(bi.w, bj.w);
        float inter = fmaxf(xx2 - xx1, 0.0f) * fmaxf(yy2 - yy1, 0.0f);
        float uni = ai + ar[j] - inter;
        float iou = inter / fmaxf(uni, 1e-8f);
        if (iou > 0.5f) bits |= (1ull << jj);
      }
    }
    sup[(size_t)i * NW + w] = bits;
    rcnt += __shfl_xor(rcnt, 1, 64);
    rcnt += __shfl_xor(rcnt, 2, 64);
    rcnt += __shfl_xor(rcnt, 4, 64);
    rcnt += __shfl_xor(rcnt, 8, 64);
    if (w == 0) rank_g[i] = rcnt;  // released by the fence below
  }
  // ---- ticket: release sup+rank rows, last of the 16 blocks resolves
  __threadfence();
  __syncthreads();
  if (t == 0) {
    unsigned done = __hip_atomic_fetch_add(&meta[1], 1u, __ATOMIC_ACQ_REL,
                                           __HIP_MEMORY_SCOPE_AGENT);
    s_last = (done == gridDim.x - 1) ? 1 : 0;
    s_chg = 0;
  }
  __syncthreads();
  if (!s_last) return;
  __threadfence();  // acquire: other blocks' sup/rank rows visible
  // ---- last block: coalesced rank load (fused-rank replaces the old
  // 1024x1024 LDS rank loop)
  unsigned rnk = __hip_atomic_load(&rank_g[t], __ATOMIC_RELAXED,
                                   __HIP_MEMORY_SCOPE_AGENT);
  if (t < 32) { keptm[t] = 0u; notm[t] = 0u; }
  bool active = (ck != 0ull) && (rnk < NK);
  bool decided = (!active) || (!valid);
  ull rw[NW];  // fully unrolled static indexing only -> registers, not scratch
#pragma unroll
  for (int w = 0; w < NW; ++w)
    rw[w] = __hip_atomic_load(&sup[(size_t)t * NW + w], __ATOMIC_RELAXED,
                              __HIP_MEMORY_SCOPE_AGENT);
  __syncthreads();
  // pad slots, rank>=NK ties, and invalid-score rows are force-dropped here,
  // so they can never suppress (not in keptm) and never stall pot (in notm).
  if (decided) atomicOr(&notm[t >> 5], 1u << (t & 31));
  __syncthreads();
  // ---- monotone-fixpoint greedy NMS (order = ck desc; relation pre-masked
  // by ckj>cki in the bitmatrix). 3-barrier rounds: s_chg=1 writes pre-B1,
  // break-read in stable region B1..B2, t0 reset post-B2 (round-7 lesson).
  for (int round = 0; round < NS; ++round) {
    if (!decided) {
      ull hit = 0ull, pot = 0ull;
#pragma unroll
      for (int w = 0; w < NW; ++w) {
        ull km = ((ull)keptm[2 * w + 1] << 32) | (ull)keptm[2 * w];
        ull nm = ((ull)notm[2 * w + 1] << 32) | (ull)notm[2 * w];
        hit |= rw[w] & km;
        pot |= rw[w] & ~(km | nm);
      }
      if (hit) {
        decided = true;
        atomicOr(&notm[t >> 5], 1u << (t & 31));
        s_chg = 1;  // benign race: all writers store 1
      } else if (!pot) {
        decided = true;
        atomicOr(&keptm[t >> 5], 1u << (t & 31));
        s_chg = 1;
      }
    }
    __syncthreads();
    if (s_chg == 0) break;
    __syncthreads();
    if (t == 0) s_chg = 0;
    __syncthreads();
  }
  // ---- argmax class (kept rows only) + output write at rank position
  if (active) {
    bool kp = (keptm[t >> 5] >> (t & 31)) & 1u;
    int ci = 0;
    if (kp) {
      unsigned a = ~(unsigned)(ck & 0xFFFFFFFFull);
      const float* row = cla + (size_t)a * NCLS;
      float m = -3.402823466e38f;
#pragma unroll
      for (int j = 0; j < NCLS; ++j) {
        float v = row[j];
        if (v > m) { m = v; ci = j; }
      }
    }
    out[rnk] = kp ? score : 0.0f;
    out[NK + rnk] = kp ? (float)ci : -1.0f;  // int output read as float
    float4 bo = bx[t];
    ((float4*)(out + 2 * NK))[rnk] = kp ? bo : make_float4(0.f, 0.f, 0.f, 0.f);
  }
}

extern "C" void kernel_launch(void* const* d_in, const int* in_sizes, int n_in,
                              void* d_out, int out_size, void* d_ws, size_t ws_size,
                              hipStream_t stream) {
  const float* cla = (const float*)d_in[0];
  const float* reg = (const float*)d_in[1];
  const float* anchors = (const float*)d_in[2];
  const int* hp = (const int*)d_in[3];
  const int* wp = (const int*)d_in[4];
  float* out = (float*)d_out;
  int A = in_sizes[2] / 4;  // 441936

  char* ws = (char*)d_ws;
  size_t off = 0;
  auto carve = [&](size_t bytes) -> void* {
    void* p = ws + off;
    off += bytes;
    off = (off + 255) & ~(size_t)255;
    return p;
  };
  unsigned* keys = (unsigned*)carve((size_t)A * 4);
  unsigned* hist0 = (unsigned*)carve(4096 * 4);  // zeroed by the memset node
  // contiguous region zeroed inside k_score: leaf|summary|meta|cand_keys
  char* zbase = ws + off;
  unsigned* leaf = (unsigned*)carve((size_t)(1 << 20) * 4);  // 4 MB
  unsigned* summary = (unsigned*)carve(4096 * 4);
  unsigned* meta = (unsigned*)carve(8 * 4);  // [0]=cand_count [1]=ticket
  ull* cand_keys = (ull*)carve(CAP * 8);
  size_t zbytes = (size_t)((ws + off) - zbase);
  int nz4 = (int)(zbytes / 16);
  ull* sup = (ull*)carve((size_t)NS * NW * 8);
  unsigned* rank_g = (unsigned*)carve(NS * 4);  // fully written by k_supdec
  (void)ws_size;
  (void)n_in;
  (void)out_size;

  hipMemsetAsync(hist0, 0, 4096 * 4, stream);
  k_score<<<1024, 256, 0, stream>>>(cla, keys, hist0, (uint4*)zbase, nz4, A);
  k_hist1<<<512, 256, 0, stream>>>(keys, hist0, leaf, summary, A);
  k_gather<<<512, 256, 0, stream>>>(keys, hist0, leaf, summary, meta, cand_keys, A);
  k_supdec<<<16, 1024, 0, stream>>>(cla, reg, anchors, hp, wp, cand_keys, sup,
                                    rank_g, meta, out);
}